// Round 3
// baseline (148.714 us; speedup 1.0000x reference)
//
#include <hip/hip_runtime.h>

// Problem constants
#define VD 160           // vol D=H=W
#define OD 128           // output crop size
#define CROP0 16         // (160-128)/2
#define FSZ 11           // cropped field size
#define RAWSZ 15         // raw field size
#define NBATCH 4
#define ODQ 4            // outputs per thread along od

// precomputed e-table: [c][od][oh][EPAD]; EPAD=16 -> shift-only addressing
#define EPAD 16
#define E_K  (OD*EPAD)        // 2048   (od stride)
#define E_C  (OD*OD*EPAD)     // 262144 (channel stride)

// ---------------------------------------------------------------------------
// Compile-time (box-5 edge-clamp)^4 as a 15x15 matrix: 4 smoothing iterations
// per axis collapse into one 15-tap linear pass (operators on distinct axes
// commute; per-axis operator is B^4).
// ---------------------------------------------------------------------------
struct M15 { float v[15][15]; };
constexpr M15 mkB() {
    M15 b{};
    for (int i = 0; i < 15; ++i)
        for (int j = 0; j < 15; ++j) b.v[i][j] = 0.0f;
    for (int i = 0; i < 15; ++i)
        for (int t = -2; t <= 2; ++t) {
            int j = i + t; j = j < 0 ? 0 : (j > 14 ? 14 : j);
            b.v[i][j] += 0.2f;
        }
    return b;
}
constexpr M15 mmul(const M15& a, const M15& b) {
    M15 c{};
    for (int i = 0; i < 15; ++i)
        for (int j = 0; j < 15; ++j) {
            float s = 0.0f;
            for (int k = 0; k < 15; ++k) s += a.v[i][k] * b.v[k][j];
            c.v[i][j] = s;
        }
    return c;
}
constexpr M15 B2 = mmul(mkB(), mkB());
constexpr M15 B4 = mmul(B2, B2);

// ---------------------------------------------------------------------------
// Kernel 1: field prep (blocks 0..2) + Rodrigues/theta (block 3).
// 3 matrix passes (x,y,z) + crop folded in.
// ---------------------------------------------------------------------------
__global__ __launch_bounds__(1024) void prep_kernel(
        const float* __restrict__ rot, const float* __restrict__ scale,
        const float* __restrict__ shift,
        const float* __restrict__ dz, const float* __restrict__ dy,
        const float* __restrict__ dx,
        float* __restrict__ theta, float* __restrict__ fields) {
    const int tid = threadIdx.x;
    const int chan = blockIdx.x;

    if (chan == 3) {
        int n = tid;
        if (n >= NBATCH) return;
        float rx = rot[n*3+0], ry = rot[n*3+1], rz = rot[n*3+2];
        float t2 = rx*rx + ry*ry + rz*rz;
        const float eps = 1e-6f;
        float th = sqrtf(fmaxf(t2, eps));
        float inv = 1.0f / (th + eps);
        float wx = rx*inv, wy = ry*inv, wz = rz*inv;
        float c = cosf(th), s = sinf(th), k = 1.0f - c;
        float R[9];
        if (t2 > eps) {
            R[0] = c + wx*wx*k;      R[1] = wx*wy*k - wz*s;  R[2] = wy*s + wx*wz*k;
            R[3] = wz*s + wx*wy*k;   R[4] = c + wy*wy*k;     R[5] = -wx*s + wy*wz*k;
            R[6] = -wy*s + wx*wz*k;  R[7] = wx*s + wy*wz*k;  R[8] = c + wz*wz*k;
        } else {
            R[0] = 1.0f; R[1] = -rz;  R[2] = ry;
            R[3] = rz;   R[4] = 1.0f; R[5] = -rx;
            R[6] = -ry;  R[7] = rx;   R[8] = 1.0f;
        }
        for (int i = 0; i < 3; ++i) {
            for (int j = 0; j < 3; ++j)
                theta[n*12 + i*4 + j] = R[i*3 + j] * scale[n*3 + j];
            theta[n*12 + i*4 + 3] = shift[n*3 + i];
        }
        return;
    }

    __shared__ float bufA[RAWSZ*RAWSZ*RAWSZ];   // raw scaled  [z][y][x]
    __shared__ float bufB[RAWSZ*RAWSZ*FSZ];     // x-pass out  [z][y][xo]
    __shared__ float bufC[RAWSZ*FSZ*FSZ];       // y-pass out  [z][yo][xo]
    const float* raw = (chan == 0) ? dz : (chan == 1) ? dy : dx;
    const int NTOT = RAWSZ*RAWSZ*RAWSZ;   // 3375

    for (int i = tid; i < NTOT; i += 1024)
        bufA[i] = (raw[i] - 0.5f) * 4.0f;
    __syncthreads();

    // x pass: 15*15*11 = 2475 outputs; out xo = crop row xo+2 of B4
    for (int i = tid; i < RAWSZ*RAWSZ*FSZ; i += 1024) {
        const int zy = i / FSZ;
        const int xo = i % FSZ;
        const float* row = &bufA[zy * RAWSZ];
        const float* w = B4.v[xo + 2];
        float s = 0.0f;
        #pragma unroll
        for (int j = 0; j < RAWSZ; ++j) s += row[j] * w[j];
        bufB[i] = s;
    }
    __syncthreads();

    // y pass: 15*11*11 = 1815 outputs
    for (int i = tid; i < RAWSZ*FSZ*FSZ; i += 1024) {
        const int z  = i / (FSZ*FSZ);
        const int r  = i % (FSZ*FSZ);
        const int yo = r / FSZ;
        const int xo = r % FSZ;
        const float* base = &bufB[z * (RAWSZ*FSZ) + xo];
        const float* w = B4.v[yo + 2];
        float s = 0.0f;
        #pragma unroll
        for (int j = 0; j < RAWSZ; ++j) s += base[j * FSZ] * w[j];
        bufC[i] = s;
    }
    __syncthreads();

    // z pass: 11*11*11 = 1331 outputs -> fields
    for (int i = tid; i < FSZ*FSZ*FSZ; i += 1024) {
        const int zo = i / (FSZ*FSZ);
        const int r  = i % (FSZ*FSZ);
        const float* base = &bufC[r];
        const float* w = B4.v[zo + 2];
        float s = 0.0f;
        #pragma unroll
        for (int j = 0; j < RAWSZ; ++j) s += base[j * (FSZ*FSZ)] * w[j];
        fields[chan*FSZ*FSZ*FSZ + i] = s;
    }
}

// ---------------------------------------------------------------------------
// resize helper: src = (m+0.5)*(11/160) - 0.5, clipped to [0,10]
// ---------------------------------------------------------------------------
__device__ __forceinline__ void resize_coord(int m, int& i0, int& i1, float& w) {
    float s = fmaf((float)m + 0.5f, (float)FSZ / (float)VD, -0.5f);
    s = fminf(fmaxf(s, 0.0f), (float)(FSZ - 1));
    float f = floorf(s);
    i0 = (int)f;
    i1 = min(i0 + 1, FSZ - 1);
    w = s - f;
}

// ---------------------------------------------------------------------------
// Kernel 1.5: materialize e-table [c][od][oh][EPAD] = 80 * zy-bilinear of the
// displacement field at the 11 x-knots. 3.1 MB, L2-resident for sampling.
// Removes the per-block e-fill + __syncthreads convoy from sample_kernel.
// ---------------------------------------------------------------------------
__global__ __launch_bounds__(128) void etab_kernel(
        const float* __restrict__ fields, float* __restrict__ etab) {
    const int od = blockIdx.x;       // 0..127
    const int oh = threadIdx.x;      // 0..127
    int zi0, zi1, yi0, yi1; float zw, yw;
    resize_coord(od + CROP0, zi0, zi1, zw);
    resize_coord(oh + CROP0, yi0, yi1, yw);
    const float w00 = (1.0f-zw)*(1.0f-yw), w01 = (1.0f-zw)*yw;
    const float w10 = zw*(1.0f-yw),        w11 = zw*yw;
    #pragma unroll
    for (int c = 0; c < 3; ++c) {
        const float* f = fields + c * (FSZ*FSZ*FSZ);
        const float* r00 = f + zi0*121 + yi0*11;
        const float* r01 = f + zi0*121 + yi1*11;
        const float* r10 = f + zi1*121 + yi0*11;
        const float* r11 = f + zi1*121 + yi1*11;
        float vv[EPAD];
        #pragma unroll
        for (int xi = 0; xi < FSZ; ++xi)
            vv[xi] = 80.0f * (r00[xi]*w00 + r01[xi]*w01 + r10[xi]*w10 + r11[xi]*w11);
        #pragma unroll
        for (int xi = FSZ; xi < EPAD; ++xi) vv[xi] = 0.0f;
        float4* dst = (float4*)(etab + ((size_t)c*OD + od)*E_K + (size_t)oh*EPAD);
        #pragma unroll
        for (int q = 0; q < EPAD/4; ++q)
            dst[q] = make_float4(vv[4*q], vv[4*q+1], vv[4*q+2], vv[4*q+3]);
    }
}

// ---------------------------------------------------------------------------
// Kernel 2: main sampler. NO LDS, NO barrier this round.
// Wave lane map = 16(ow) x 4(oh); block = 512 thr = 8 waves (2wx x 2wh x 2wd);
// block tile = 32(w) x 8(h) x 8(d); each thread does ODQ=4 od's.
// Load schedule FORCED with sched_barrier(0) fences:
//   cluster(24 e-loads) | fence | coords | cluster(16 vol gathers) | fence |
//   consume.  (R2 post-mortem: compiler re-serialized the batched loads to
//   keep VGPR=32; fences make it hold all results live -> real MLP.)
// grid = (OD/32, OD/8, (OD/8)*NBATCH).
// ---------------------------------------------------------------------------
__global__ __launch_bounds__(512, 4) void sample_kernel(
        const float* __restrict__ vol, const float* __restrict__ theta,
        const float* __restrict__ etab, float* __restrict__ out) {
    const int tid  = threadIdx.x;
    const int lane = tid & 63;
    const int wl   = lane & 15;        // x within wave patch
    const int hl   = lane >> 4;        // y within wave patch (0..3)
    const int wv   = tid >> 6;         // wave id 0..7
    const int wx   = wv & 1;
    const int wh   = (wv >> 1) & 1;
    const int wd   = wv >> 2;          // 0..1

    const int ow   = (blockIdx.x << 5) | (wx << 4) | wl;   // 0..127
    const int oh   = (blockIdx.y << 3) | (wh << 2) | hl;   // 0..127
    const int odb  = (blockIdx.z & 15) << 3;               // od block base
    const int n    = blockIdx.z >> 4;
    const int od0  = odb + (wd << 2);

    const int w_ = ow + CROP0;

    const float x = fmaf(2.0f * (float)w_ + 1.0f, 1.0f / (float)VD, -1.0f);
    const float y = fmaf(2.0f * (float)(oh + CROP0) + 1.0f, 1.0f / (float)VD, -1.0f);

    // x-knot: s in [0.63, 9.38] for valid w_ -> xi0<=9, xi1=xi0+1 always
    float s = fmaf((float)w_ + 0.5f, (float)FSZ / (float)VD, -0.5f);
    s = fminf(fmaxf(s, 0.0f), (float)(FSZ - 1));
    const float sf = floorf(s);
    const int   xi0 = (int)sf;
    const float xw  = s - sf;

    const float* th = theta + n*12;
    const float cx = fmaf(th[0]*x + th[1]*y + th[3], 80.0f, 79.5f);
    const float cy = fmaf(th[4]*x + th[5]*y + th[7], 80.0f, 79.5f);
    const float cz = fmaf(th[8]*x + th[9]*y + th[11], 80.0f, 79.5f);
    const float tz0 = th[2] * 80.0f, tz1 = th[6] * 80.0f, tz2 = th[10] * 80.0f;

    const float* v = vol + (size_t)n * (VD*VD*VD);

    // ---- cluster 1: all 24 e-loads issued before any use ----
    const float* ep = etab + (size_t)od0*E_K + (size_t)oh*EPAD + xi0;
    float e0[3][ODQ], e1[3][ODQ];
    #pragma unroll
    for (int c = 0; c < 3; ++c)
        #pragma unroll
        for (int k = 0; k < ODQ; ++k) {
            e0[c][k] = ep[c*E_C + k*E_K    ];
            e1[c][k] = ep[c*E_C + k*E_K + 1];
        }
    __builtin_amdgcn_sched_barrier(0);

    // ---- batched coords ----
    const float zb = fmaf(2.0f * (float)(od0 + CROP0) + 1.0f,
                          1.0f / (float)VD, -1.0f);
    float fx[ODQ], fy[ODQ], fz[ODQ];
    int ix[ODQ], iy[ODQ], iz[ODQ];
    int inb = 1;
    #pragma unroll
    for (int k = 0; k < ODQ; ++k) {
        const float z = zb + (float)k * (2.0f / (float)VD);
        const float d80x = fmaf(e1[0][k] - e0[0][k], xw, e0[0][k]);
        const float d80y = fmaf(e1[1][k] - e0[1][k], xw, e0[1][k]);
        const float d80z = fmaf(e1[2][k] - e0[2][k], xw, e0[2][k]);
        const float xs = fmaf(tz0, z, cx) + d80x;
        const float ys = fmaf(tz1, z, cy) + d80y;
        const float zs = fmaf(tz2, z, cz) + d80z;
        const float x0f = floorf(xs), y0f = floorf(ys), z0f = floorf(zs);
        fx[k] = xs - x0f; fy[k] = ys - y0f; fz[k] = zs - z0f;
        ix[k] = (int)x0f; iy[k] = (int)y0f; iz[k] = (int)z0f;
        inb &= ((unsigned)ix[k] < (unsigned)(VD-1)) &
               ((unsigned)iy[k] < (unsigned)(VD-1)) &
               ((unsigned)iz[k] < (unsigned)(VD-1));
    }

    float* op = out + ((((size_t)n*OD + od0)*OD + oh)*OD + ow);

    if (__all(inb)) {
        // ---- cluster 2: ALL 16 gathers issued before consumption ----
        float2 p00[ODQ], p01[ODQ], p10[ODQ], p11[ODQ];
        #pragma unroll
        for (int k = 0; k < ODQ; ++k) {
            const int b00 = (iz[k]*VD + iy[k])*VD + ix[k];
            __builtin_memcpy(&p00[k], v + b00,            sizeof(float2));
            __builtin_memcpy(&p01[k], v + b00 + VD,       sizeof(float2));
            __builtin_memcpy(&p10[k], v + b00 + VD*VD,    sizeof(float2));
            __builtin_memcpy(&p11[k], v + b00 + VD*VD+VD, sizeof(float2));
        }
        __builtin_amdgcn_sched_barrier(0);
        #pragma unroll
        for (int k = 0; k < ODQ; ++k) {
            const float r00 = fmaf(fx[k], p00[k].y - p00[k].x, p00[k].x);
            const float r01 = fmaf(fx[k], p01[k].y - p01[k].x, p01[k].x);
            const float r10 = fmaf(fx[k], p10[k].y - p10[k].x, p10[k].x);
            const float r11 = fmaf(fx[k], p11[k].y - p11[k].x, p11[k].x);
            const float r0 = fmaf(fy[k], r01 - r00, r00);
            const float r1 = fmaf(fy[k], r11 - r10, r10);
            op[(size_t)k*OD*OD] = fmaf(fz[k], r1 - r0, r0);
        }
    } else {
        // ---- border path: full predicated weights + clamps (rare) ----
        #pragma unroll
        for (int k = 0; k < ODQ; ++k) {
            const int ix1 = ix[k] + 1, iy1 = iy[k] + 1, iz1 = iz[k] + 1;

            const float WX0 = ((unsigned)ix[k] < (unsigned)VD) ? (1.0f - fx[k]) : 0.0f;
            const float WX1 = ((unsigned)ix1   < (unsigned)VD) ? fx[k]          : 0.0f;
            const float WY0 = ((unsigned)iy[k] < (unsigned)VD) ? (1.0f - fy[k]) : 0.0f;
            const float WY1 = ((unsigned)iy1   < (unsigned)VD) ? fy[k]          : 0.0f;
            const float WZ0 = ((unsigned)iz[k] < (unsigned)VD) ? (1.0f - fz[k]) : 0.0f;
            const float WZ1 = ((unsigned)iz1   < (unsigned)VD) ? fz[k]          : 0.0f;

            const int xc0 = min(max(ix[k], 0), VD-1), xc1 = min(max(ix1, 0), VD-1);
            const int yc0 = min(max(iy[k], 0), VD-1), yc1 = min(max(iy1, 0), VD-1);
            const int zc0 = min(max(iz[k], 0), VD-1), zc1 = min(max(iz1, 0), VD-1);

            // one dwordx2 covers both x-taps; fold x-selection into wA/wB
            const int base = min(xc0, VD-2);
            const bool hi0 = (xc0 != base);
            const bool hi1 = (xc1 != base);
            const float wA = (hi0 ? 0.0f : WX0) + (hi1 ? 0.0f : WX1);
            const float wB = (hi0 ? WX0 : 0.0f) + (hi1 ? WX1 : 0.0f);

            const int sA = zc0*(VD*VD), sB = zc1*(VD*VD);
            const int tA = yc0*VD + base, tB = yc1*VD + base;

            float2 p00, p01, p10, p11;
            __builtin_memcpy(&p00, v + sA + tA, sizeof(float2));
            __builtin_memcpy(&p01, v + sA + tB, sizeof(float2));
            __builtin_memcpy(&p10, v + sB + tA, sizeof(float2));
            __builtin_memcpy(&p11, v + sB + tB, sizeof(float2));

            const float r00 = p00.x*wA + p00.y*wB;
            const float r01 = p01.x*wA + p01.y*wB;
            const float r10 = p10.x*wA + p10.y*wB;
            const float r11 = p11.x*wA + p11.y*wB;
            op[(size_t)k*OD*OD] = (r00*WY0 + r01*WY1)*WZ0 + (r10*WY0 + r11*WY1)*WZ1;
        }
    }
}

// ---------------------------------------------------------------------------
extern "C" void kernel_launch(void* const* d_in, const int* in_sizes, int n_in,
                              void* d_out, int out_size, void* d_ws, size_t ws_size,
                              hipStream_t stream) {
    const float* vol   = (const float*)d_in[0];
    const float* rot   = (const float*)d_in[1];
    const float* scale = (const float*)d_in[2];
    const float* shift = (const float*)d_in[3];
    const float* dz    = (const float*)d_in[4];
    const float* dy    = (const float*)d_in[5];
    const float* dx    = (const float*)d_in[6];
    float* out = (float*)d_out;

    float* ws     = (float*)d_ws;
    float* theta  = ws;          // 48 floats
    float* fields = ws + 48;     // 3*1331 = 3993 floats
    float* etab   = ws + 4096;   // 16B-aligned; 3*128*128*16 floats = 3.1 MB

    prep_kernel<<<4, 1024, 0, stream>>>(rot, scale, shift, dz, dy, dx,
                                        theta, fields);
    etab_kernel<<<OD, 128, 0, stream>>>(fields, etab);
    dim3 grid(OD/32, OD/8, (OD/8)*NBATCH);
    sample_kernel<<<grid, 512, 0, stream>>>(vol, theta, etab, out);
}

// Round 4
// 139.592 us; speedup vs baseline: 1.0654x; 1.0654x over previous
//
#include <hip/hip_runtime.h>

// Problem constants
#define VD 160           // vol D=H=W
#define OD 128           // output crop size
#define CROP0 16         // (160-128)/2
#define FSZ 11           // cropped field size
#define RAWSZ 15         // raw field size
#define NBATCH 4
#define ODQ 4            // outputs per thread along od

// e-table (LDS): rows [c(3)][oh_l(4)][od_l(8)], row stride ESTR floats.
#define ESTR 17
#define E_CST (32*ESTR)    // channel stride = 544 floats

// ---------------------------------------------------------------------------
// Compile-time (box-5 edge-clamp)^4 as a 15x15 matrix: 4 smoothing iterations
// per axis collapse into one 15-tap linear pass (operators on distinct axes
// commute; per-axis operator is B^4).
// ---------------------------------------------------------------------------
struct M15 { float v[15][15]; };
constexpr M15 mkB() {
    M15 b{};
    for (int i = 0; i < 15; ++i)
        for (int j = 0; j < 15; ++j) b.v[i][j] = 0.0f;
    for (int i = 0; i < 15; ++i)
        for (int t = -2; t <= 2; ++t) {
            int j = i + t; j = j < 0 ? 0 : (j > 14 ? 14 : j);
            b.v[i][j] += 0.2f;
        }
    return b;
}
constexpr M15 mmul(const M15& a, const M15& b) {
    M15 c{};
    for (int i = 0; i < 15; ++i)
        for (int j = 0; j < 15; ++j) {
            float s = 0.0f;
            for (int k = 0; k < 15; ++k) s += a.v[i][k] * b.v[k][j];
            c.v[i][j] = s;
        }
    return c;
}
constexpr M15 B2 = mmul(mkB(), mkB());
constexpr M15 B4 = mmul(B2, B2);

// ---------------------------------------------------------------------------
// Kernel 1: field prep (blocks 0..2) + Rodrigues/theta (block 3).
// 3 matrix passes (x,y,z) + crop folded in.
// ---------------------------------------------------------------------------
__global__ __launch_bounds__(1024) void prep_kernel(
        const float* __restrict__ rot, const float* __restrict__ scale,
        const float* __restrict__ shift,
        const float* __restrict__ dz, const float* __restrict__ dy,
        const float* __restrict__ dx,
        float* __restrict__ theta, float* __restrict__ fields) {
    const int tid = threadIdx.x;
    const int chan = blockIdx.x;

    if (chan == 3) {
        int n = tid;
        if (n >= NBATCH) return;
        float rx = rot[n*3+0], ry = rot[n*3+1], rz = rot[n*3+2];
        float t2 = rx*rx + ry*ry + rz*rz;
        const float eps = 1e-6f;
        float th = sqrtf(fmaxf(t2, eps));
        float inv = 1.0f / (th + eps);
        float wx = rx*inv, wy = ry*inv, wz = rz*inv;
        float c = cosf(th), s = sinf(th), k = 1.0f - c;
        float R[9];
        if (t2 > eps) {
            R[0] = c + wx*wx*k;      R[1] = wx*wy*k - wz*s;  R[2] = wy*s + wx*wz*k;
            R[3] = wz*s + wx*wy*k;   R[4] = c + wy*wy*k;     R[5] = -wx*s + wy*wz*k;
            R[6] = -wy*s + wx*wz*k;  R[7] = wx*s + wy*wz*k;  R[8] = c + wz*wz*k;
        } else {
            R[0] = 1.0f; R[1] = -rz;  R[2] = ry;
            R[3] = rz;   R[4] = 1.0f; R[5] = -rx;
            R[6] = -ry;  R[7] = rx;   R[8] = 1.0f;
        }
        for (int i = 0; i < 3; ++i) {
            for (int j = 0; j < 3; ++j)
                theta[n*12 + i*4 + j] = R[i*3 + j] * scale[n*3 + j];
            theta[n*12 + i*4 + 3] = shift[n*3 + i];
        }
        return;
    }

    __shared__ float bufA[RAWSZ*RAWSZ*RAWSZ];   // raw scaled  [z][y][x]
    __shared__ float bufB[RAWSZ*RAWSZ*FSZ];     // x-pass out  [z][y][xo]
    __shared__ float bufC[RAWSZ*FSZ*FSZ];       // y-pass out  [z][yo][xo]
    const float* raw = (chan == 0) ? dz : (chan == 1) ? dy : dx;
    const int NTOT = RAWSZ*RAWSZ*RAWSZ;   // 3375

    for (int i = tid; i < NTOT; i += 1024)
        bufA[i] = (raw[i] - 0.5f) * 4.0f;
    __syncthreads();

    // x pass: 15*15*11 = 2475 outputs; out xo = crop row xo+2 of B4
    for (int i = tid; i < RAWSZ*RAWSZ*FSZ; i += 1024) {
        const int zy = i / FSZ;
        const int xo = i % FSZ;
        const float* row = &bufA[zy * RAWSZ];
        const float* w = B4.v[xo + 2];
        float s = 0.0f;
        #pragma unroll
        for (int j = 0; j < RAWSZ; ++j) s += row[j] * w[j];
        bufB[i] = s;
    }
    __syncthreads();

    // y pass: 15*11*11 = 1815 outputs
    for (int i = tid; i < RAWSZ*FSZ*FSZ; i += 1024) {
        const int z  = i / (FSZ*FSZ);
        const int r  = i % (FSZ*FSZ);
        const int yo = r / FSZ;
        const int xo = r % FSZ;
        const float* base = &bufB[z * (RAWSZ*FSZ) + xo];
        const float* w = B4.v[yo + 2];
        float s = 0.0f;
        #pragma unroll
        for (int j = 0; j < RAWSZ; ++j) s += base[j * FSZ] * w[j];
        bufC[i] = s;
    }
    __syncthreads();

    // z pass: 11*11*11 = 1331 outputs -> fields
    for (int i = tid; i < FSZ*FSZ*FSZ; i += 1024) {
        const int zo = i / (FSZ*FSZ);
        const int r  = i % (FSZ*FSZ);
        const float* base = &bufC[r];
        const float* w = B4.v[zo + 2];
        float s = 0.0f;
        #pragma unroll
        for (int j = 0; j < RAWSZ; ++j) s += base[j * (FSZ*FSZ)] * w[j];
        fields[chan*FSZ*FSZ*FSZ + i] = s;
    }
}

// ---------------------------------------------------------------------------
// resize helper: src = (m+0.5)*(11/160) - 0.5, clipped to [0,10]
// ---------------------------------------------------------------------------
__device__ __forceinline__ void resize_coord(int m, int& i0, int& i1, float& w) {
    float s = fmaf((float)m + 0.5f, (float)FSZ / (float)VD, -0.5f);
    s = fminf(fmaxf(s, 0.0f), (float)(FSZ - 1));
    float f = floorf(s);
    i0 = (int)f;
    i1 = min(i0 + 1, FSZ - 1);
    w = s - f;
}

// ---------------------------------------------------------------------------
// Kernel 2: main sampler.
// NEW wave map this round: each wave = 64 consecutive ow (one x-row) -> each
// gather instruction's lanes span one contiguous ~280B run (was 4 separate
// y-rows), stores are fully-coalesced 256B, e-reads broadcast within a row.
// Block = 512 thr = 8 waves = 4(oh) x 2(wd); block tile = 64w x 4h x 8d;
// each thread does ODQ=4 od's.
// e-table back in LDS (r3 global etab cost +23MB HBM = 8 XCD refetch).
// MLP forced with asm liveness pins: all 16 gathers must be issued before
// the first s_waitcnt (r2/r3: compiler collapsed clusters, VGPR stayed 32).
// grid = (OD/64, OD/4, (OD/8)*NBATCH).
// ---------------------------------------------------------------------------
__global__ __launch_bounds__(512, 4) void sample_kernel(
        const float* __restrict__ vol, const float* __restrict__ theta,
        const float* __restrict__ fields, float* __restrict__ out) {
    __shared__ float e[3*E_CST];   // 96 rows x 17 floats = 6528 B

    const int tid  = threadIdx.x;
    const int lane = tid & 63;
    const int wv   = tid >> 6;         // wave id 0..7
    const int oh_l = wv & 3;
    const int wd   = wv >> 2;          // 0..1

    const int ow   = (blockIdx.x << 6) | lane;      // 0..127
    const int oh   = (blockIdx.y << 2) | oh_l;      // 0..127
    const int odb  = (blockIdx.z & 15) << 3;        // od block base
    const int n    = blockIdx.z >> 4;
    const int od0  = odb + (wd << 2);

    // ---- e fill: 32 rows (oh_l*8+od_l) x 16 xi slots = 512 threads exactly;
    //      3 channels per thread; resize_coord hoisted (2 calls) ----
    {
        const int xi = tid & 15;
        const int rb = tid >> 4;        // 0..31 = oh_l*8 + od_l
        if (xi < FSZ) {
            const int od_l  = rb & 7;
            const int oh_l2 = rb >> 3;
            int zi0, zi1, yi0, yi1; float zw, yw;
            resize_coord(odb + od_l + CROP0, zi0, zi1, zw);
            resize_coord((blockIdx.y << 2) + oh_l2 + CROP0, yi0, yi1, yw);
            const float w00 = (1.0f-zw)*(1.0f-yw), w01 = (1.0f-zw)*yw;
            const float w10 = zw*(1.0f-yw),        w11 = zw*yw;
            const int o00 = zi0*121 + yi0*11 + xi, o01 = zi0*121 + yi1*11 + xi;
            const int o10 = zi1*121 + yi0*11 + xi, o11 = zi1*121 + yi1*11 + xi;
            #pragma unroll
            for (int c = 0; c < 3; ++c) {
                const float* f = fields + c * (FSZ*FSZ*FSZ);
                e[(c*32 + rb)*ESTR + xi] =
                    80.0f * (f[o00]*w00 + f[o01]*w01 + f[o10]*w10 + f[o11]*w11);
            }
        }
    }

    // ---- per-thread setup (before barrier: overlaps e-fill latency) ----
    const int w_ = ow + CROP0;

    const float x = fmaf(2.0f * (float)w_ + 1.0f, 1.0f / (float)VD, -1.0f);
    const float y = fmaf(2.0f * (float)(oh + CROP0) + 1.0f, 1.0f / (float)VD, -1.0f);

    // x-knot: s in [0.63, 9.38] for valid w_ -> xi0<=9, xi1=xi0+1 always
    float s = fmaf((float)w_ + 0.5f, (float)FSZ / (float)VD, -0.5f);
    s = fminf(fmaxf(s, 0.0f), (float)(FSZ - 1));
    const float sf = floorf(s);
    const int   xi0 = (int)sf;
    const float xw  = s - sf;

    const float* th = theta + n*12;
    const float cx = fmaf(th[0]*x + th[1]*y + th[3], 80.0f, 79.5f);
    const float cy = fmaf(th[4]*x + th[5]*y + th[7], 80.0f, 79.5f);
    const float cz = fmaf(th[8]*x + th[9]*y + th[11], 80.0f, 79.5f);
    const float tz0 = th[2] * 80.0f, tz1 = th[6] * 80.0f, tz2 = th[10] * 80.0f;

    const float* v = vol + (size_t)n * (VD*VD*VD);

    // row = oh_l*8 + wd*4 (+k); channel stride E_CST
    const float* ebase = &e[(oh_l*8 + (wd << 2))*ESTR + xi0];

    const float zb = fmaf(2.0f * (float)(od0 + CROP0) + 1.0f,
                          1.0f / (float)VD, -1.0f);
    float* op = out + ((((size_t)n*OD + od0)*OD + oh)*OD + ow);

    __syncthreads();

    // ---- batched e reads: 12 pairs, all independent ----
    float e0[3][ODQ], e1[3][ODQ];
    #pragma unroll
    for (int c = 0; c < 3; ++c)
        #pragma unroll
        for (int k = 0; k < ODQ; ++k) {
            e0[c][k] = ebase[c*E_CST + k*ESTR    ];
            e1[c][k] = ebase[c*E_CST + k*ESTR + 1];
        }

    // ---- batched coords ----
    float fx[ODQ], fy[ODQ], fz[ODQ];
    int ix[ODQ], iy[ODQ], iz[ODQ];
    int inb = 1;
    #pragma unroll
    for (int k = 0; k < ODQ; ++k) {
        const float z = zb + (float)k * (2.0f / (float)VD);
        const float d80x = fmaf(e1[0][k] - e0[0][k], xw, e0[0][k]);
        const float d80y = fmaf(e1[1][k] - e0[1][k], xw, e0[1][k]);
        const float d80z = fmaf(e1[2][k] - e0[2][k], xw, e0[2][k]);
        const float xs = fmaf(tz0, z, cx) + d80x;
        const float ys = fmaf(tz1, z, cy) + d80y;
        const float zs = fmaf(tz2, z, cz) + d80z;
        const float x0f = floorf(xs), y0f = floorf(ys), z0f = floorf(zs);
        fx[k] = xs - x0f; fy[k] = ys - y0f; fz[k] = zs - z0f;
        ix[k] = (int)x0f; iy[k] = (int)y0f; iz[k] = (int)z0f;
        inb &= ((unsigned)ix[k] < (unsigned)(VD-1)) &
               ((unsigned)iy[k] < (unsigned)(VD-1)) &
               ((unsigned)iz[k] < (unsigned)(VD-1));
    }

    if (__all(inb)) {
        // ---- ALL 16 gathers issued, then PINNED live before consumption ----
        float2 p00[ODQ], p01[ODQ], p10[ODQ], p11[ODQ];
        #pragma unroll
        for (int k = 0; k < ODQ; ++k) {
            const int b00 = (iz[k]*VD + iy[k])*VD + ix[k];
            __builtin_memcpy(&p00[k], v + b00,            sizeof(float2));
            __builtin_memcpy(&p01[k], v + b00 + VD,       sizeof(float2));
            __builtin_memcpy(&p10[k], v + b00 + VD*VD,    sizeof(float2));
            __builtin_memcpy(&p11[k], v + b00 + VD*VD+VD, sizeof(float2));
        }
        __builtin_amdgcn_sched_barrier(0);
        // liveness pins: each value must be materialized in a VGPR here, so
        // no load can be sunk below this point -> 16 loads in flight.
        #pragma unroll
        for (int k = 0; k < ODQ; ++k)
            asm volatile("" :: "v"(p00[k].x), "v"(p00[k].y),
                               "v"(p01[k].x), "v"(p01[k].y),
                               "v"(p10[k].x), "v"(p10[k].y),
                               "v"(p11[k].x), "v"(p11[k].y));
        #pragma unroll
        for (int k = 0; k < ODQ; ++k) {
            const float r00 = fmaf(fx[k], p00[k].y - p00[k].x, p00[k].x);
            const float r01 = fmaf(fx[k], p01[k].y - p01[k].x, p01[k].x);
            const float r10 = fmaf(fx[k], p10[k].y - p10[k].x, p10[k].x);
            const float r11 = fmaf(fx[k], p11[k].y - p11[k].x, p11[k].x);
            const float r0 = fmaf(fy[k], r01 - r00, r00);
            const float r1 = fmaf(fy[k], r11 - r10, r10);
            op[(size_t)k*OD*OD] = fmaf(fz[k], r1 - r0, r0);
        }
    } else {
        // ---- border path: full predicated weights + clamps (rare) ----
        #pragma unroll
        for (int k = 0; k < ODQ; ++k) {
            const int ix1 = ix[k] + 1, iy1 = iy[k] + 1, iz1 = iz[k] + 1;

            const float WX0 = ((unsigned)ix[k] < (unsigned)VD) ? (1.0f - fx[k]) : 0.0f;
            const float WX1 = ((unsigned)ix1   < (unsigned)VD) ? fx[k]          : 0.0f;
            const float WY0 = ((unsigned)iy[k] < (unsigned)VD) ? (1.0f - fy[k]) : 0.0f;
            const float WY1 = ((unsigned)iy1   < (unsigned)VD) ? fy[k]          : 0.0f;
            const float WZ0 = ((unsigned)iz[k] < (unsigned)VD) ? (1.0f - fz[k]) : 0.0f;
            const float WZ1 = ((unsigned)iz1   < (unsigned)VD) ? fz[k]          : 0.0f;

            const int xc0 = min(max(ix[k], 0), VD-1), xc1 = min(max(ix1, 0), VD-1);
            const int yc0 = min(max(iy[k], 0), VD-1), yc1 = min(max(iy1, 0), VD-1);
            const int zc0 = min(max(iz[k], 0), VD-1), zc1 = min(max(iz1, 0), VD-1);

            // one dwordx2 covers both x-taps; fold x-selection into wA/wB
            const int base = min(xc0, VD-2);
            const bool hi0 = (xc0 != base);
            const bool hi1 = (xc1 != base);
            const float wA = (hi0 ? 0.0f : WX0) + (hi1 ? 0.0f : WX1);
            const float wB = (hi0 ? WX0 : 0.0f) + (hi1 ? WX1 : 0.0f);

            const int sA = zc0*(VD*VD), sB = zc1*(VD*VD);
            const int tA = yc0*VD + base, tB = yc1*VD + base;

            float2 p00, p01, p10, p11;
            __builtin_memcpy(&p00, v + sA + tA, sizeof(float2));
            __builtin_memcpy(&p01, v + sA + tB, sizeof(float2));
            __builtin_memcpy(&p10, v + sB + tA, sizeof(float2));
            __builtin_memcpy(&p11, v + sB + tB, sizeof(float2));

            const float r00 = p00.x*wA + p00.y*wB;
            const float r01 = p01.x*wA + p01.y*wB;
            const float r10 = p10.x*wA + p10.y*wB;
            const float r11 = p11.x*wA + p11.y*wB;
            op[(size_t)k*OD*OD] = (r00*WY0 + r01*WY1)*WZ0 + (r10*WY0 + r11*WY1)*WZ1;
        }
    }
}

// ---------------------------------------------------------------------------
extern "C" void kernel_launch(void* const* d_in, const int* in_sizes, int n_in,
                              void* d_out, int out_size, void* d_ws, size_t ws_size,
                              hipStream_t stream) {
    const float* vol   = (const float*)d_in[0];
    const float* rot   = (const float*)d_in[1];
    const float* scale = (const float*)d_in[2];
    const float* shift = (const float*)d_in[3];
    const float* dz    = (const float*)d_in[4];
    const float* dy    = (const float*)d_in[5];
    const float* dx    = (const float*)d_in[6];
    float* out = (float*)d_out;

    float* ws     = (float*)d_ws;
    float* theta  = ws;          // 48 floats
    float* fields = ws + 48;     // 3*1331 = 3993 floats

    prep_kernel<<<4, 1024, 0, stream>>>(rot, scale, shift, dz, dy, dx,
                                        theta, fields);
    dim3 grid(OD/64, OD/4, (OD/8)*NBATCH);
    sample_kernel<<<grid, 512, 0, stream>>>(vol, theta, fields, out);
}